// Round 9
// baseline (1923.376 us; speedup 1.0000x reference)
//
#include <hip/hip_runtime.h>
#include <stdint.h>

typedef unsigned short u16;
typedef unsigned int   u32;
typedef __attribute__((ext_vector_type(4)))  short s4v;
typedef __attribute__((ext_vector_type(8)))  short s8v;
typedef __attribute__((ext_vector_type(16))) float f16v;

#define JJ 17
#define CC 128
#define BB 3
#define ROWS (BB*JJ)     // 51
#define PP 64
#define XP 136           // u16 pitch: 272B rows -> every frag 16B-aligned (b128)
#define NLAYERS 5
#define NT 256

#define XH_OFF   0
#define XL_OFF   (PP*XP*2)        // 17408
#define MH_OFF   (2*PP*XP*2)      // 34816
#define ML_OFF   (3*PP*XP*2)      // 52224
#define ADJ_OFF  (4*PP*XP*2)      // 69632
#define DIAG_OFF (ADJ_OFF + 1216) // 70848
#define LDS_BYTES (DIAG_OFF + 256) // 71104 -> 2 blocks/CU (142208 <= 160K)

#define MFMA __builtin_amdgcn_mfma_f32_32x32x16_bf16

__device__ __forceinline__ u16 f2bf(float f) {
  u32 u = __float_as_uint(f);
  u += 0x7FFFu + ((u >> 16) & 1u);   // RNE
  return (u16)(u >> 16);
}
__device__ __forceinline__ float bf2f(u16 h) {
  return __uint_as_float(((u32)h) << 16);
}
__device__ __forceinline__ float wred(float v) {
  #pragma unroll
  for (int m = 32; m >= 1; m >>= 1) v += __shfl_xor(v, m, 64);
  return v;
}
__device__ __forceinline__ s8v u4s8(uint4 v) {
  union { uint4 u; s8v s; } c; c.u = v; return c.s;
}

// ---- setup: split W0/W1 into hi/lo bf16 planes, frag layout ws[w][col][k] ----
__global__ void __launch_bounds__(256)
wprep(const float* __restrict__ W0, const float* __restrict__ W1,
      u16* __restrict__ wsH, u16* __restrict__ wsL)
{
  __shared__ float wt[64*130];
  const int w01 = blockIdx.x;
  const float* Wp = w01 ? W1 : W0;
  const int tid = threadIdx.x;
  for (int kh = 0; kh < 2; ++kh) {
    if (kh) __syncthreads();
    #pragma unroll
    for (int i = 0; i < 32; ++i) {
      int idx = tid + i*256;           // [64 kk][128 col] coalesced read
      int kk = idx >> 7, col = idx & 127;
      wt[kk*130 + col] = Wp[(kh*64 + kk)*128 + col];
    }
    __syncthreads();
    #pragma unroll
    for (int i = 0; i < 32; ++i) {
      int idx = tid + i*256;           // [128 col][64 kk] coalesced write
      int col = idx >> 6, kk = idx & 63;
      float v = wt[kk*130 + col];
      u16 h = f2bf(v);
      size_t o = (size_t)(w01*128 + col)*128 + kh*64 + kk;
      wsH[o] = h;
      wsL[o] = f2bf(v - bf2f(h));
    }
  }
}

__global__ void __launch_bounds__(NT, 2)
gconv_fused(const float* __restrict__ x, const float* __restrict__ x0,
            const float* __restrict__ adj, const u16* __restrict__ wsH,
            const u16* __restrict__ wsL, const float* __restrict__ bvec,
            const float* __restrict__ gamma, const float* __restrict__ beta,
            float* __restrict__ out, int totRows)
{
  extern __shared__ char smem[];
  u16*   xh    = (u16*)(smem + XH_OFF);     // [PP][XP] x hi
  u16*   xl    = (u16*)(smem + XL_OFF);     // x lo
  u16*   mhp   = (u16*)(smem + MH_OFF);     // Xm = A_off*X, hi
  u16*   mlp   = (u16*)(smem + ML_OFF);     // Xm lo
  float* adjs  = (float*)(smem + ADJ_OFF);  // [289] 0.8*adj, diag zeroed
  float* diag8 = (float*)(smem + DIAG_OFF); // [64]

  const int tid  = threadIdx.x;
  const int lane = tid & 63;
  const int wid  = tid >> 6;        // 0..3 = N-tile
  const int g    = lane >> 5;
  const int nl   = lane & 31;
  const int ccol = wid*32 + nl;
  const int grow0 = blockIdx.x * ROWS;

  // ---- whi straight to regs from precomputed ws (L2-hot)
  s8v whi[2][8];
  #pragma unroll
  for (int w01 = 0; w01 < 2; ++w01) {
    const u16* bh = wsH + (size_t)(w01*128 + ccol)*128;
    #pragma unroll
    for (int ks = 0; ks < 8; ++ks)
      whi[w01][ks] = u4s8(*(const uint4*)&bh[ks*16 + 8*g]);
  }
  const float bias_c = bvec[ccol];

  // ---- x -> xh/xl planes; pad rows zero (64 rows x 32 float4 = 2048)
  #pragma unroll
  for (int i = 0; i < 8; ++i) {
    int el4 = tid + i*NT;
    int r = el4 >> 5, c4 = (el4 & 31) << 2;
    float4 v = make_float4(0.f, 0.f, 0.f, 0.f);
    if (r < ROWS && (grow0 + r) < totRows)
      v = *(const float4*)&x[(size_t)(grow0 + r)*CC + c4];
    s4v sh, sl;
    float vv[4] = {v.x, v.y, v.z, v.w};
    #pragma unroll
    for (int e = 0; e < 4; ++e) {
      u16 hh = f2bf(vv[e]);
      sh[e] = (short)hh;
      sl[e] = (short)f2bf(vv[e] - bf2f(hh));
    }
    *(s4v*)&xh[r*XP + c4] = sh;
    *(s4v*)&xl[r*XP + c4] = sl;
  }
  // zero Xm pad rows (51..63) once
  for (int idx = tid; idx < (PP-ROWS)*XP; idx += NT) {
    int rr = idx / XP, c = idx - rr*XP;
    mhp[(ROWS+rr)*XP + c] = 0;
    mlp[(ROWS+rr)*XP + c] = 0;
  }
  for (int t = tid; t < JJ*JJ; t += NT) {
    int j = t / JJ, k = t - j*JJ;
    adjs[t] = (j == k) ? 0.f : 0.8f * adj[t];
  }
  if (tid < PP) {
    int j = tid % JJ;
    diag8[tid] = (tid < ROWS) ? 0.8f * adj[j*JJ + j] : 0.f;
  }
  __syncthreads();

  const u16* pL0 = wsL + (size_t)ccol*128 + 8*g;          // w01=0 lo frags
  const u16* pL1 = wsL + (size_t)(128 + ccol)*128 + 8*g;  // w01=1

  // ================= layer loop: {mix | GEMM | combine} =================
  #pragma unroll 1
  for (int layer = 0; layer < NLAYERS; ++layer) {
    // ---- mix first: Xm[b,j,:] = sum_k adjs[j,k] * X[b,k,:]  (384 col-jobs)
    {
      auto mixjob = [&](int jb) {
        int e = jb >> 7, c = jb & 127;
        int base = e*JJ*XP + c;
        float xv[JJ];
        #pragma unroll
        for (int k = 0; k < JJ; ++k)
          xv[k] = bf2f(xh[base + k*XP]) + bf2f(xl[base + k*XP]);
        for (int j = 0; j < JJ; ++j) {
          float s = 0.f;
          #pragma unroll
          for (int k = 0; k < JJ; ++k) s += adjs[j*JJ + k] * xv[k];
          u16 hh = f2bf(s);
          mhp[base + j*XP] = hh;
          mlp[base + j*XP] = f2bf(s - bf2f(hh));
        }
      };
      mixjob(tid);
      if (tid < 128) mixjob(tid + NT);
    }
    __syncthreads();

    // ---- GEMM: acc0 = X*W0, acc1 = Xm*W1 (3-product bf16 split each)
    f16v acc0[2], acc1[2];
    #pragma unroll
    for (int mt = 0; mt < 2; ++mt)
      #pragma unroll
      for (int i = 0; i < 16; ++i) { acc0[mt][i] = 0.f; acc1[mt][i] = 0.f; }

    s8v r0[3], r1[3];                  // 3-deep static W-lo ring from global (L2)
    r0[0] = u4s8(*(const uint4*)(pL0));      r1[0] = u4s8(*(const uint4*)(pL1));
    r0[1] = u4s8(*(const uint4*)(pL0 + 16)); r1[1] = u4s8(*(const uint4*)(pL1 + 16));
    r0[2] = u4s8(*(const uint4*)(pL0 + 32)); r1[2] = u4s8(*(const uint4*)(pL1 + 32));
    #pragma unroll
    for (int ks = 0; ks < 8; ++ks) {
      #pragma unroll
      for (int mt = 0; mt < 2; ++mt) {
        const int xb = (mt*32 + nl)*XP + ks*16 + 8*g;
        s8v ah  = *(const s8v*)&xh[xb];
        s8v al  = *(const s8v*)&xl[xb];
        s8v amh = *(const s8v*)&mhp[xb];
        s8v aml = *(const s8v*)&mlp[xb];
        acc0[mt] = MFMA(ah,  whi[0][ks], acc0[mt], 0, 0, 0);
        acc0[mt] = MFMA(al,  whi[0][ks], acc0[mt], 0, 0, 0);
        acc0[mt] = MFMA(ah,  r0[ks%3],   acc0[mt], 0, 0, 0);
        acc1[mt] = MFMA(amh, whi[1][ks], acc1[mt], 0, 0, 0);
        acc1[mt] = MFMA(aml, whi[1][ks], acc1[mt], 0, 0, 0);
        acc1[mt] = MFMA(amh, r1[ks%3],   acc1[mt], 0, 0, 0);
      }
      if (ks < 5) {                    // refill ring slot just freed
        r0[ks%3] = u4s8(*(const uint4*)(pL0 + (ks+3)*16));
        r1[ks%3] = u4s8(*(const uint4*)(pL1 + (ks+3)*16));
      }
      __builtin_amdgcn_sched_barrier(0);   // cap fragment liveness per K-step
    }
    __syncthreads();               // X/Xm reads done before X overwrite

    // ---- combine: x' = 0.2*x0 + diag*acc0 + acc1 + b  -> split to xh/xl
    #pragma unroll
    for (int mt = 0; mt < 2; ++mt) {
      float x0v[16];
      #pragma unroll
      for (int q = 0; q < 16; ++q) {
        int row = mt*32 + (q&3) + 8*(q>>2) + 4*g;
        int grow = grow0 + row;
        x0v[q] = (row < ROWS && grow < totRows) ? x0[(size_t)grow*CC + ccol] : 0.f;
      }
      #pragma unroll
      for (int q = 0; q < 16; ++q) {
        int row = mt*32 + (q&3) + 8*(q>>2) + 4*g;
        float v = 0.2f*x0v[q] + diag8[row]*acc0[mt][q] + acc1[mt][q] + bias_c;
        u16 hh = f2bf(v);
        xh[row*XP + ccol] = hh;
        xl[row*XP + ccol] = f2bf(v - bf2f(hh));
      }
    }
    __syncthreads();
  }

  // ---- LayerNorm + store
  float ga = gamma[lane], g2 = gamma[64+lane];
  float ba = beta[lane],  b2 = beta[64+lane];
  #pragma unroll 1
  for (int i = 0; i < 13; ++i) {
    int r = wid + 4*i;               // wave-uniform
    if (r >= ROWS) continue;
    int grow = grow0 + r;
    if (grow >= totRows) continue;
    int xb = r*XP;
    float xa = bf2f(xh[xb+lane])    + bf2f(xl[xb+lane]);
    float xc = bf2f(xh[xb+64+lane]) + bf2f(xl[xb+64+lane]);
    float mu = wred(xa + xc) * (1.f/128.f);
    float da = xa - mu, dc = xc - mu;
    float vs = wred(da*da + dc*dc) * (1.f/128.f);
    float rs = rsqrtf(vs + 1e-10f);
    size_t ob = (size_t)grow*CC;
    out[ob + lane]      = da*rs*ga + ba;
    out[ob + 64 + lane] = dc*rs*g2 + b2;
  }
}

extern "C" void kernel_launch(void* const* d_in, const int* in_sizes, int n_in,
                              void* d_out, int out_size, void* d_ws, size_t ws_size,
                              hipStream_t stream) {
  const float* x   = (const float*)d_in[0];
  const float* x0  = (const float*)d_in[1];
  const float* adj = (const float*)d_in[2];
  const float* W0  = (const float*)d_in[3];
  const float* W1  = (const float*)d_in[4];
  const float* bv  = (const float*)d_in[5];
  const float* ga  = (const float*)d_in[6];
  const float* be  = (const float*)d_in[7];
  u16* wsH = (u16*)d_ws;                    // [2][128][128] bf16 hi
  u16* wsL = wsH + 2*128*128;               // [2][128][128] bf16 lo
  int totRows = in_sizes[0] / CC;
  int nBatch  = totRows / JJ;
  int grid    = (nBatch + BB - 1) / BB;
  wprep<<<dim3(2), dim3(256), 0, stream>>>(W0, W1, wsH, wsL);
  hipFuncSetAttribute((const void*)gconv_fused,
                      hipFuncAttributeMaxDynamicSharedMemorySize, LDS_BYTES);
  gconv_fused<<<dim3(grid), dim3(NT), LDS_BYTES, stream>>>(
      x, x0, adj, wsH, wsL, bv, ga, be, (float*)d_out, totRows);
}

// Round 10
// 698.137 us; speedup vs baseline: 2.7550x; 2.7550x over previous
//
#include <hip/hip_runtime.h>
#include <stdint.h>

typedef unsigned short u16;
typedef unsigned int   u32;
typedef _Float16 f16x8 __attribute__((ext_vector_type(8)));
typedef __attribute__((ext_vector_type(16))) float f16v;
typedef __attribute__((ext_vector_type(2)))  float f2v;

#define JJ 17
#define CC 128
#define BB 7
#define ROWS (BB*JJ)     // 119
#define PP 128
#define XP 136           // u16 pitch: 272B rows -> every frag 16B-aligned (b128)
#define H1P 130          // f32 pitch for h1 (aliases X planes)
#define NLAYERS 5
#define NT 512

#define XBUF_BYTES (2*PP*XP*2)           // 69632: xh+xl u16 planes; h1 f32[128][130]=66560 alias
#define ADJS_OFF   XBUF_BYTES            // 69632
#define DIAG_OFF   (ADJS_OFF + 1216)     // 70848
#define BIAS_OFF   (DIAG_OFF + 512)      // 71360
#define LDS_BYTES  (BIAS_OFF + 512)      // 71872 -> 2 blocks/CU (143744 <= 163840)

#define MFMA __builtin_amdgcn_mfma_f32_32x32x16_f16

__device__ __forceinline__ u16 h2b(_Float16 h) {
  union { _Float16 h; u16 b; } c; c.h = h; return c.b;
}
__device__ __forceinline__ _Float16 b2h(u16 b) {
  union { u16 b; _Float16 h; } c; c.b = b; return c.h;
}
__device__ __forceinline__ float wred(float v) {
  #pragma unroll
  for (int m = 32; m >= 1; m >>= 1) v += __shfl_xor(v, m, 64);
  return v;
}
__device__ __forceinline__ f16x8 u4f8(uint4 v) {
  union { uint4 u; f16x8 f; } c; c.u = v; return c.f;
}

// ---- setup: W0/W1 -> f16, frag layout ws[w][col][k] ----
__global__ void __launch_bounds__(256)
wprep(const float* __restrict__ W0, const float* __restrict__ W1,
      u16* __restrict__ wsH)
{
  __shared__ float wt[64*130];
  const int w01 = blockIdx.x;
  const float* Wp = w01 ? W1 : W0;
  const int tid = threadIdx.x;
  for (int kh = 0; kh < 2; ++kh) {
    if (kh) __syncthreads();
    #pragma unroll
    for (int i = 0; i < 32; ++i) {
      int idx = tid + i*256;           // [64 kk][128 col] coalesced read
      int kk = idx >> 7, col = idx & 127;
      wt[kk*130 + col] = Wp[(kh*64 + kk)*128 + col];
    }
    __syncthreads();
    #pragma unroll
    for (int i = 0; i < 32; ++i) {
      int idx = tid + i*256;           // [128 col][64 kk] coalesced write
      int col = idx >> 6, kk = idx & 63;
      wsH[(size_t)(w01*128 + col)*128 + kh*64 + kk] = h2b((_Float16)wt[kk*130 + col]);
    }
  }
}

__global__ void __launch_bounds__(NT, 2)
gconv_fused(const float* __restrict__ x, const float* __restrict__ x0,
            const float* __restrict__ adj, const u16* __restrict__ wsH,
            const float* __restrict__ bvec, const float* __restrict__ gamma,
            const float* __restrict__ beta, float* __restrict__ out, int totRows)
{
  extern __shared__ char smem[];
  u16*   xh    = (u16*)smem;                   // [PP][XP] x hi (f16)
  u16*   xl    = xh + PP*XP;                   // x lo (f16)
  float* h1    = (float*)smem;                 // alias, [PP][H1P] f32
  float* adjs  = (float*)(smem + ADJS_OFF);    // [289] 0.8*adj, diag zeroed
  float* diag8 = (float*)(smem + DIAG_OFF);    // [128]
  float* biasl = (float*)(smem + BIAS_OFF);    // [128]

  const int tid  = threadIdx.x;
  const int lane = tid & 63;
  const int wid  = tid >> 6;        // 0..7
  const int wm   = wid >> 2;        // 0..1  (M half)
  const int wn   = wid & 3;         // 0..3  (N tile)
  const int g    = lane >> 5;
  const int nl   = lane & 31;
  const int ccol = wn*32 + nl;
  const int grow0 = blockIdx.x * ROWS;

  // ---- W (f16) straight to regs from precomputed ws (L2-hot): 64 VGPRs total
  f16x8 whi[2][8];
  #pragma unroll
  for (int w01 = 0; w01 < 2; ++w01) {
    const u16* bh = wsH + (size_t)(w01*128 + ccol)*128;
    #pragma unroll
    for (int ks = 0; ks < 8; ++ks)
      whi[w01][ks] = u4f8(*(const uint4*)&bh[ks*16 + 8*g]);
  }

  // ---- x0 -> 16 packed-f16 regs (accumulator layout), read once
  u32 x0p[2][8];
  #pragma unroll
  for (int mt = 0; mt < 2; ++mt)
    #pragma unroll
    for (int qp = 0; qp < 8; ++qp) {
      u32 pk = 0;
      #pragma unroll
      for (int h = 0; h < 2; ++h) {
        int q = qp*2 + h;
        int row = wm*64 + mt*32 + (q&3) + 8*(q>>2) + 4*g;
        int grow = grow0 + row;
        u16 bits = 0;
        if (row < ROWS && grow < totRows)
          bits = h2b((_Float16)x0[(size_t)grow*CC + ccol]);
        pk |= ((u32)bits) << (16*h);
      }
      x0p[mt][qp] = pk;
    }

  // ---- x -> xh/xl f16 planes (float4 in); pad rows zero
  #pragma unroll
  for (int i = 0; i < 8; ++i) {
    int el4 = tid + i*NT;              // 4096 float4 = 128 rows x 128
    int r = el4 >> 5, c4 = (el4 & 31) << 2;
    float4 v = make_float4(0.f, 0.f, 0.f, 0.f);
    if (r < ROWS && (grow0 + r) < totRows)
      v = *(const float4*)&x[(size_t)(grow0 + r)*CC + c4];
    u16 sh[4], sl[4];
    float vv[4] = {v.x, v.y, v.z, v.w};
    #pragma unroll
    for (int e = 0; e < 4; ++e) {
      _Float16 hh = (_Float16)vv[e];
      sh[e] = h2b(hh);
      sl[e] = h2b((_Float16)(vv[e] - (float)hh));
    }
    *(uint2*)&xh[r*XP + c4] = make_uint2((u32)sh[0] | ((u32)sh[1]<<16), (u32)sh[2] | ((u32)sh[3]<<16));
    *(uint2*)&xl[r*XP + c4] = make_uint2((u32)sl[0] | ((u32)sl[1]<<16), (u32)sl[2] | ((u32)sl[3]<<16));
  }
  if (tid < JJ*JJ) {
    int j = tid / JJ, k = tid - j*JJ;
    adjs[tid] = (j == k) ? 0.f : 0.8f * adj[tid];
  }
  if (tid < PP) {
    int j = tid % JJ;
    diag8[tid] = (tid < ROWS) ? 0.8f * adj[j*JJ + j] : 0.f;
  }
  if (tid >= 128 && tid < 256) biasl[tid - 128] = bvec[tid - 128];
  __syncthreads();

  // ================= layer loop (LDS/regs only — no global) =================
  #pragma unroll 1
  for (int layer = 0; layer < NLAYERS; ++layer) {
    f16v acc0[2], acc1[2];
    #pragma unroll
    for (int mt = 0; mt < 2; ++mt)
      #pragma unroll
      for (int i = 0; i < 16; ++i) { acc0[mt][i] = 0.f; acc1[mt][i] = 0.f; }

    // ---- GEMM: per ks per mt: 2x ds_read_b128 + 4 MFMA
    #pragma unroll
    for (int ks = 0; ks < 8; ++ks) {
      #pragma unroll
      for (int mt = 0; mt < 2; ++mt) {
        const int xb = (wm*64 + mt*32 + nl)*XP + ks*16 + 8*g;
        f16x8 ah = *(const f16x8*)&xh[xb];
        f16x8 al = *(const f16x8*)&xl[xb];
        acc0[mt] = MFMA(ah, whi[0][ks], acc0[mt], 0, 0, 0);
        acc0[mt] = MFMA(al, whi[0][ks], acc0[mt], 0, 0, 0);
        acc1[mt] = MFMA(ah, whi[1][ks], acc1[mt], 0, 0, 0);
        acc1[mt] = MFMA(al, whi[1][ks], acc1[mt], 0, 0, 0);
      }
      __builtin_amdgcn_sched_barrier(0);   // cap fragment liveness per K-step
    }
    __syncthreads();               // xh/xl reads done (h1 aliases them)

    // ---- epilogue: acc1 (X@W1) -> h1
    #pragma unroll
    for (int mt = 0; mt < 2; ++mt)
      #pragma unroll
      for (int q = 0; q < 16; ++q) {
        int row = wm*64 + mt*32 + (q&3) + 8*(q>>2) + 4*g;
        h1[row*H1P + ccol] = acc1[mt][q];
      }
    __syncthreads();

    // ---- joint mix in place (wave wid = batch elem; wave 7 idles)
    if (wid < BB) {
      const int rb = wid * JJ;
      f2v h[JJ];
      #pragma unroll
      for (int k = 0; k < JJ; ++k)
        h[k] = *(const f2v*)&h1[(rb+k)*H1P + 2*lane];
      #pragma unroll 2
      for (int j = 0; j < JJ; ++j) {
        f2v m; m.x = 0.f; m.y = 0.f;
        #pragma unroll
        for (int k = 0; k < JJ; ++k) {
          float a = adjs[j*JJ + k];
          m.x += a * h[k].x; m.y += a * h[k].y;
        }
        *(f2v*)&h1[(rb+j)*H1P + 2*lane] = m;
      }
    }
    __syncthreads();

    // ---- combine A: gather into regs (x0 from registers)
    float tmp[2][16];
    #pragma unroll
    for (int mt = 0; mt < 2; ++mt)
      #pragma unroll
      for (int q = 0; q < 16; ++q) {
        int row = wm*64 + mt*32 + (q&3) + 8*(q>>2) + 4*g;
        float x0v = (float)b2h((u16)(x0p[mt][q>>1] >> (16*(q&1))));
        tmp[mt][q] = 0.2f*x0v + diag8[row]*acc0[mt][q] + h1[row*H1P + ccol] + biasl[ccol];
      }
    __syncthreads();               // h1 reads done before xh/xl overwrite

    // ---- combine B: write new x split (f16 hi/lo)
    #pragma unroll
    for (int mt = 0; mt < 2; ++mt)
      #pragma unroll
      for (int q = 0; q < 16; ++q) {
        int row = wm*64 + mt*32 + (q&3) + 8*(q>>2) + 4*g;
        _Float16 hh = (_Float16)tmp[mt][q];
        xh[row*XP + ccol] = h2b(hh);
        xl[row*XP + ccol] = h2b((_Float16)(tmp[mt][q] - (float)hh));
      }
    __syncthreads();
  }

  // ---- LayerNorm + store
  float ga = gamma[lane], g2 = gamma[64+lane];
  float ba = beta[lane],  b2f = beta[64+lane];
  #pragma unroll 1
  for (int i = 0; i < 16; ++i) {
    int r = wid + 8*i;             // wave-uniform
    if (r >= ROWS) continue;
    int grow = grow0 + r;
    if (grow >= totRows) continue;
    int xb = r*XP;
    float xa = (float)b2h(xh[xb+lane])    + (float)b2h(xl[xb+lane]);
    float xc = (float)b2h(xh[xb+64+lane]) + (float)b2h(xl[xb+64+lane]);
    float mu = wred(xa + xc) * (1.f/128.f);
    float da = xa - mu, dc = xc - mu;
    float vs = wred(da*da + dc*dc) * (1.f/128.f);
    float rs = rsqrtf(vs + 1e-10f);
    size_t ob = (size_t)grow*CC;
    out[ob + lane]      = da*rs*ga + ba;
    out[ob + 64 + lane] = dc*rs*g2 + b2f;
  }
}

extern "C" void kernel_launch(void* const* d_in, const int* in_sizes, int n_in,
                              void* d_out, int out_size, void* d_ws, size_t ws_size,
                              hipStream_t stream) {
  const float* x   = (const float*)d_in[0];
  const float* x0  = (const float*)d_in[1];
  const float* adj = (const float*)d_in[2];
  const float* W0  = (const float*)d_in[3];
  const float* W1  = (const float*)d_in[4];
  const float* bv  = (const float*)d_in[5];
  const float* ga  = (const float*)d_in[6];
  const float* be  = (const float*)d_in[7];
  u16* wsH = (u16*)d_ws;                    // [2][128][128] f16
  int totRows = in_sizes[0] / CC;
  int nBatch  = totRows / JJ;
  int grid    = (nBatch + BB - 1) / BB;
  wprep<<<dim3(2), dim3(256), 0, stream>>>(W0, W1, wsH);
  hipFuncSetAttribute((const void*)gconv_fused,
                      hipFuncAttributeMaxDynamicSharedMemorySize, LDS_BYTES);
  gconv_fused<<<dim3(grid), dim3(NT), LDS_BYTES, stream>>>(
      x, x0, adj, wsH, bv, ga, be, (float*)d_out, totRows);
}